// Round 4
// baseline (22.926 us; speedup 1.0000x reference)
//
#include <hip/hip_runtime.h>
#include <hip/hip_bf16.h>
#include <math.h>

// DIAGNOSTIC ROUND: kernel is byte-identical to R3. We dispatch it 3x
// back-to-back (idempotent writes -> output unchanged) to separate fixed
// measurement/launch overhead from true marginal kernel cost:
//   k = (dur_R4 - dur_R3) / 2
//
// h[d, l] = 2*Re( sum_n C[d,n] * exp(dtA[d,n] * l) )
// Factor l = i + 16*j: h[d][i+16j] = Re( sum_n S[n][i] * T[n][j] ),
// S single A-fragment, T walked 16 cols/tile via *= z^256; two f16 MFMA
// 16x16x32 per tile; contiguous 1KB wave-stores.

constexpr int D_MODEL = 1024;
constexpr int NMODES  = 32;
constexpr int SEQLEN  = 4096;
constexpr int WAVES_PER_D = 2;
constexpr int TILES_PER_WAVE = 16 / WAVES_PER_D;   // 8 tiles of 16 j-columns

typedef _Float16 half8 __attribute__((ext_vector_type(8)));
typedef float    f32x4 __attribute__((ext_vector_type(4)));

__global__ __launch_bounds__(256, 2)
void modal_mfma_kernel(const float* __restrict__ log_dt,
                       const float* __restrict__ C_ri,
                       const float* __restrict__ inv_A_real,
                       const float* __restrict__ A_imag,
                       float* __restrict__ out)
{
    const int wave = (blockIdx.x * 256 + (int)threadIdx.x) >> 6;
    const int lane = threadIdx.x & 63;
    const int d    = wave / WAVES_PER_D;
    const int half = wave % WAVES_PER_D;
    const int tj0  = half * TILES_PER_WAVE;
    const int g    = lane >> 4;              // k-group (modes 8g..8g+7)
    const int q    = lane & 15;              // A: row m=i ; B: col n=j-offset
    const float qf = (float)q;

    const float dt = __expf(log_dt[d]);

    half8 Sr, Si;                            // A fragments (i = q)
    float wr[8], wi[8], yr[8], yi[8];        // T walkers + per-tile step z^256

#pragma unroll
    for (int e = 0; e < 8; ++e) {
        const int k   = 8 * g + e;
        const int idx = d * NMODES + k;
        const float a   = -__expf(inv_A_real[idx]) * dt;   // Re(dtA)
        const float b   = A_imag[idx] * dt;                // Im(dtA)
        const float cr2 = 2.0f * C_ri[2 * idx + 0];
        const float ci2 = 2.0f * C_ri[2 * idx + 1];

        // S[k][q] = C2 * z^q
        float s, c;
        const float ea = __expf(a * qf);
        __sincosf(b * qf, &s, &c);
        Sr[e] = (_Float16)(ea * (cr2 * c - ci2 * s));
        Si[e] = (_Float16)(ea * (cr2 * s + ci2 * c));

        // T walker base: z^(16*(16*tj0 + q))
        const float j0 = 16.0f * (16.0f * (float)tj0 + qf);
        float sw, cw;
        const float ew = __expf(a * j0);
        __sincosf(b * j0, &sw, &cw);
        wr[e] = ew * cw;
        wi[e] = ew * sw;

        // per-tile step: z^256
        float sy, cy;
        const float ey = __expf(256.0f * a);
        __sincosf(256.0f * b, &sy, &cy);
        yr[e] = ey * cy;
        yi[e] = ey * sy;
    }

    // store base: floats offset = 16*j + i = 256*tj + 16*q + 4*g (+reg)
    float* od = out + (size_t)d * SEQLEN + 256 * tj0 + 16 * q + 4 * g;

#pragma unroll
    for (int t = 0; t < TILES_PER_WAVE; ++t) {
        half8 Trh, Tih;
#pragma unroll
        for (int e = 0; e < 8; ++e) {
            Trh[e] = (_Float16)wr[e];
            Tih[e] = (_Float16)(-wi[e]);
            const float nr = wr[e] * yr[e] - wi[e] * yi[e];
            wi[e] = wr[e] * yi[e] + wi[e] * yr[e];
            wr[e] = nr;
        }
        f32x4 acc = {0.f, 0.f, 0.f, 0.f};
        acc = __builtin_amdgcn_mfma_f32_16x16x32_f16(Sr, Trh, acc, 0, 0, 0);
        acc = __builtin_amdgcn_mfma_f32_16x16x32_f16(Si, Tih, acc, 0, 0, 0);
        *reinterpret_cast<f32x4*>(od + 256 * t) = acc;   // 64 lanes x 16B = 1KB contiguous
    }
}

extern "C" void kernel_launch(void* const* d_in, const int* in_sizes, int n_in,
                              void* d_out, int out_size, void* d_ws, size_t ws_size,
                              hipStream_t stream) {
    const float* log_dt     = (const float*)d_in[0];
    const float* C_ri       = (const float*)d_in[1];
    const float* inv_A_real = (const float*)d_in[2];
    const float* A_imag     = (const float*)d_in[3];
    float* out              = (float*)d_out;

    // 3 idempotent dispatches: dur = overhead + 3*k  (R3 was overhead + k)
    for (int rep = 0; rep < 3; ++rep) {
        modal_mfma_kernel<<<D_MODEL * WAVES_PER_D / 4, 256, 0, stream>>>(
            log_dt, C_ri, inv_A_real, A_imag, out);
    }
}

// Round 5
// 11.798 us; speedup vs baseline: 1.9432x; 1.9432x over previous
//
#include <hip/hip_runtime.h>
#include <hip/hip_bf16.h>
#include <math.h>

// h[d, l] = 2*Re( sum_n C[d,n] * exp(dtA[d,n] * l) )
// Factor l = i + 16*j: h[d][i+16j] = Re( sum_n S[n][i] * T[n][j] ),
//   S[n][i] = 2*C[d,n]*z_n^i (one A-fragment), T[n][j] = z_n^(16j) walked
//   16 cols/tile via *= z^256. Two f16 MFMA 16x16x32 per tile, K=32=NMODES.
// R4 diagnostic: marginal kernel cost ~4-6us vs 2.5us write floor, ~5us fixed
// harness overhead. This round: overlap setup with store drain —
//   (a) 4 waves/SIMD (WAVES_PER_D=4) for latency hiding / store parallelism,
//   (b) software-pipeline: tile-0 MFMA+store issued after only S+walker-base
//       trans (~500cyc), z^256 step trans deferred behind the first store
//       (sched_barrier pins it), so the drain starts early and hides the rest.

constexpr int D_MODEL = 1024;
constexpr int NMODES  = 32;
constexpr int SEQLEN  = 4096;
constexpr int WAVES_PER_D = 4;
constexpr int TILES_PER_WAVE = 16 / WAVES_PER_D;   // 4 tiles of 16 j-columns

typedef _Float16 half8 __attribute__((ext_vector_type(8)));
typedef float    f32x4 __attribute__((ext_vector_type(4)));

__global__ __launch_bounds__(256, 4)
void modal_mfma_kernel(const float* __restrict__ log_dt,
                       const float* __restrict__ C_ri,
                       const float* __restrict__ inv_A_real,
                       const float* __restrict__ A_imag,
                       float* __restrict__ out)
{
    const int wave = (blockIdx.x * 256 + (int)threadIdx.x) >> 6;
    const int lane = threadIdx.x & 63;
    const int d    = wave / WAVES_PER_D;
    const int qtr  = wave % WAVES_PER_D;
    const int tj0  = qtr * TILES_PER_WAVE;
    const int g    = lane >> 4;              // k-group (modes 8g..8g+7)
    const int q    = lane & 15;              // A: row m=i ; B: col n=j-offset
    const float qf = (float)q;

    const float dt = __expf(log_dt[d]);

    half8 Sr, Si;                            // A fragments (i = q)
    float wr[8], wi[8];                      // T walkers
    float av[8], bv[8];                      // per-mode a,b kept for step phase

#pragma unroll
    for (int e = 0; e < 8; ++e) {
        const int k   = 8 * g + e;
        const int idx = d * NMODES + k;
        const float a   = -__expf(inv_A_real[idx]) * dt;   // Re(dtA)
        const float b   = A_imag[idx] * dt;                // Im(dtA)
        const float cr2 = 2.0f * C_ri[2 * idx + 0];
        const float ci2 = 2.0f * C_ri[2 * idx + 1];
        av[e] = a; bv[e] = b;

        // S[k][q] = C2 * z^q
        float s, c;
        const float ea = __expf(a * qf);
        __sincosf(b * qf, &s, &c);
        Sr[e] = (_Float16)(ea * (cr2 * c - ci2 * s));
        Si[e] = (_Float16)(ea * (cr2 * s + ci2 * c));

        // T walker base: z^(16*(16*tj0 + q))
        const float j0 = 16.0f * (16.0f * (float)tj0 + qf);
        float sw, cw;
        const float ew = __expf(a * j0);
        __sincosf(b * j0, &sw, &cw);
        wr[e] = ew * cw;
        wi[e] = ew * sw;
    }

    // ---- tile 0: store as early as possible (starts the HBM drain) ----
    float* od = out + (size_t)d * SEQLEN + 256 * tj0 + 16 * q + 4 * g;
    {
        half8 Trh, Tih;
#pragma unroll
        for (int e = 0; e < 8; ++e) {
            Trh[e] = (_Float16)wr[e];
            Tih[e] = (_Float16)(-wi[e]);
        }
        f32x4 acc = {0.f, 0.f, 0.f, 0.f};
        acc = __builtin_amdgcn_mfma_f32_16x16x32_f16(Sr, Trh, acc, 0, 0, 0);
        acc = __builtin_amdgcn_mfma_f32_16x16x32_f16(Si, Tih, acc, 0, 0, 0);
        *reinterpret_cast<f32x4*>(od) = acc;             // 1KB contiguous / wave
    }
    __builtin_amdgcn_sched_barrier(0);  // keep step-trans below the first store

    // ---- deferred: per-tile step z^256, then walk tiles 1..3 ----
    float yr[8], yi[8];
#pragma unroll
    for (int e = 0; e < 8; ++e) {
        float sy, cy;
        const float ey = __expf(256.0f * av[e]);
        __sincosf(256.0f * bv[e], &sy, &cy);
        yr[e] = ey * cy;
        yi[e] = ey * sy;
    }

#pragma unroll
    for (int t = 1; t < TILES_PER_WAVE; ++t) {
        half8 Trh, Tih;
#pragma unroll
        for (int e = 0; e < 8; ++e) {
            const float nr = wr[e] * yr[e] - wi[e] * yi[e];
            wi[e] = wr[e] * yi[e] + wi[e] * yr[e];
            wr[e] = nr;
            Trh[e] = (_Float16)wr[e];
            Tih[e] = (_Float16)(-wi[e]);
        }
        f32x4 acc = {0.f, 0.f, 0.f, 0.f};
        acc = __builtin_amdgcn_mfma_f32_16x16x32_f16(Sr, Trh, acc, 0, 0, 0);
        acc = __builtin_amdgcn_mfma_f32_16x16x32_f16(Si, Tih, acc, 0, 0, 0);
        *reinterpret_cast<f32x4*>(od + 256 * t) = acc;
    }
}

extern "C" void kernel_launch(void* const* d_in, const int* in_sizes, int n_in,
                              void* d_out, int out_size, void* d_ws, size_t ws_size,
                              hipStream_t stream) {
    const float* log_dt     = (const float*)d_in[0];
    const float* C_ri       = (const float*)d_in[1];
    const float* inv_A_real = (const float*)d_in[2];
    const float* A_imag     = (const float*)d_in[3];
    float* out              = (float*)d_out;

    // 4096 waves = 4 per d = 1024 blocks x 4 waves (4 waves/SIMD chip-wide)
    modal_mfma_kernel<<<D_MODEL * WAVES_PER_D / 4, 256, 0, stream>>>(
        log_dt, C_ri, inv_A_real, A_imag, out);
}

// Round 6
// 11.041 us; speedup vs baseline: 2.0765x; 1.0686x over previous
//
#include <hip/hip_runtime.h>
#include <hip/hip_bf16.h>
#include <math.h>

// h[d, l] = 2*Re( sum_n C[d,n] * exp(dtA[d,n] * l) )
// Factor l = i + 16*j: h[d][i+16j] = Re( sum_n S[n][i] * T[n][j] ),
//   S[n][i] = 2*C[d,n]*z_n^i (one A-fragment), T[n][j] = z_n^(16j) walked
//   16 cols/tile via *= z^256. Two f16 MFMA 16x16x32 per tile, K=32=NMODES.
//
// R2 vs R3 showed stores are NOT the bottleneck (coalescing fix = -3%); the
// kernel is setup-latency-bound. R5 showed duplicating setup across 4 waves/d
// regresses. This round, single change vs R3: replace the 32 scalar
// global_load_dword per lane with 8 global_load_dwordx4 (16B-aligned mode
// blocks), issued as one burst at the top, so the VMEM train pipelines and
// the trans chains start sooner.

constexpr int D_MODEL = 1024;
constexpr int NMODES  = 32;
constexpr int SEQLEN  = 4096;
constexpr int WAVES_PER_D = 2;
constexpr int TILES_PER_WAVE = 16 / WAVES_PER_D;   // 8 tiles of 16 j-columns

typedef _Float16 half8 __attribute__((ext_vector_type(8)));
typedef float    f32x4 __attribute__((ext_vector_type(4)));

__global__ __launch_bounds__(256, 2)
void modal_mfma_kernel(const float* __restrict__ log_dt,
                       const float* __restrict__ C_ri,
                       const float* __restrict__ inv_A_real,
                       const float* __restrict__ A_imag,
                       float* __restrict__ out)
{
    const int wave = (blockIdx.x * 256 + (int)threadIdx.x) >> 6;
    const int lane = threadIdx.x & 63;
    const int d    = wave / WAVES_PER_D;
    const int half = wave % WAVES_PER_D;
    const int tj0  = half * TILES_PER_WAVE;
    const int g    = lane >> 4;              // k-group (modes 8g..8g+7)
    const int q    = lane & 15;              // A: row m=i ; B: col n=j-offset
    const float qf = (float)q;

    // ---- vectorized input burst: 8 x dwordx4 per lane (was 32 x dword) ----
    const int idx0 = d * NMODES + 8 * g;     // 8-mode block, 32B-aligned
    const f32x4* pA = reinterpret_cast<const f32x4*>(inv_A_real + idx0);
    const f32x4* pB = reinterpret_cast<const f32x4*>(A_imag + idx0);
    const f32x4* pC = reinterpret_cast<const f32x4*>(C_ri + 2 * idx0);
    const f32x4 Ar0 = pA[0], Ar1 = pA[1];
    const f32x4 Bi0 = pB[0], Bi1 = pB[1];
    const f32x4 Cc0 = pC[0], Cc1 = pC[1], Cc2 = pC[2], Cc3 = pC[3];

    const float dt = __expf(log_dt[d]);

    half8 Sr, Si;                            // A fragments (i = q)
    float wr[8], wi[8], yr[8], yi[8];        // T walkers + per-tile step z^256

#pragma unroll
    for (int e = 0; e < 8; ++e) {
        const float iar = (e < 4) ? Ar0[e] : Ar1[e - 4];
        const float bim = (e < 4) ? Bi0[e] : Bi1[e - 4];
        const f32x4 Cv  = (e < 2) ? Cc0 : (e < 4) ? Cc1 : (e < 6) ? Cc2 : Cc3;
        const float cr2 = 2.0f * Cv[(e & 1) * 2 + 0];
        const float ci2 = 2.0f * Cv[(e & 1) * 2 + 1];

        const float a = -__expf(iar) * dt;   // Re(dtA)
        const float b = bim * dt;            // Im(dtA)

        // S[k][q] = C2 * z^q
        float s, c;
        const float ea = __expf(a * qf);
        __sincosf(b * qf, &s, &c);
        Sr[e] = (_Float16)(ea * (cr2 * c - ci2 * s));
        Si[e] = (_Float16)(ea * (cr2 * s + ci2 * c));

        // T walker base: z^(16*(16*tj0 + q))
        const float j0 = 16.0f * (16.0f * (float)tj0 + qf);
        float sw, cw;
        const float ew = __expf(a * j0);
        __sincosf(b * j0, &sw, &cw);
        wr[e] = ew * cw;
        wi[e] = ew * sw;

        // per-tile step: z^256
        float sy, cy;
        const float ey = __expf(256.0f * a);
        __sincosf(256.0f * b, &sy, &cy);
        yr[e] = ey * cy;
        yi[e] = ey * sy;
    }

    // store base: floats offset = 16*j + i = 256*tj + 16*q + 4*g (+reg)
    float* od = out + (size_t)d * SEQLEN + 256 * tj0 + 16 * q + 4 * g;

#pragma unroll
    for (int t = 0; t < TILES_PER_WAVE; ++t) {
        half8 Trh, Tih;
#pragma unroll
        for (int e = 0; e < 8; ++e) {
            Trh[e] = (_Float16)wr[e];
            Tih[e] = (_Float16)(-wi[e]);
            const float nr = wr[e] * yr[e] - wi[e] * yi[e];
            wi[e] = wr[e] * yi[e] + wi[e] * yr[e];
            wr[e] = nr;
        }
        f32x4 acc = {0.f, 0.f, 0.f, 0.f};
        acc = __builtin_amdgcn_mfma_f32_16x16x32_f16(Sr, Trh, acc, 0, 0, 0);
        acc = __builtin_amdgcn_mfma_f32_16x16x32_f16(Si, Tih, acc, 0, 0, 0);
        *reinterpret_cast<f32x4*>(od + 256 * t) = acc;   // 1KB contiguous / wave
    }
}

extern "C" void kernel_launch(void* const* d_in, const int* in_sizes, int n_in,
                              void* d_out, int out_size, void* d_ws, size_t ws_size,
                              hipStream_t stream) {
    const float* log_dt     = (const float*)d_in[0];
    const float* C_ri       = (const float*)d_in[1];
    const float* inv_A_real = (const float*)d_in[2];
    const float* A_imag     = (const float*)d_in[3];
    float* out              = (float*)d_out;

    // 2048 waves = 2 per d = 512 blocks x 4 waves (2 waves/SIMD chip-wide)
    modal_mfma_kernel<<<D_MODEL * WAVES_PER_D / 4, 256, 0, stream>>>(
        log_dt, C_ri, inv_A_real, A_imag, out);
}